// Round 11
// baseline (1384.829 us; speedup 1.0000x reference)
//
#include <hip/hip_runtime.h>
#include <hip/hip_bf16.h>

using bf16 = __hip_bfloat16;
typedef __attribute__((ext_vector_type(8))) short short8;
typedef __attribute__((ext_vector_type(4))) short s16x4;
typedef __attribute__((ext_vector_type(4))) float f32x4;

#define MFMA(a,b,c) __builtin_amdgcn_mfma_f32_16x16x32_bf16(a, b, c, 0, 0, 0)

#define B_      128
#define C_      1024
#define NH      8
#define HD      128
#define HW      24
#define NTOK    576
#define QH      12
#define QN      144

static __device__ __forceinline__ float bf2f(bf16 v) { return __bfloat162float(v); }
static __device__ __forceinline__ bf16  f2bf(float v) { return __float2bfloat16(v); }
static __device__ __forceinline__ float s2f(short s) {
    return __uint_as_float(((unsigned)(unsigned short)s) << 16);
}
static __device__ __forceinline__ unsigned bfbits(float v) {
    bf16 t = f2bf(v);
    return (unsigned)*(unsigned short*)&t;
}

__device__ __forceinline__ void gll16(const bf16* src, bf16* dst_lds) {
    __builtin_amdgcn_global_load_lds(
        (__attribute__((address_space(1))) const unsigned int*)src,
        (__attribute__((address_space(3))) unsigned int*)dst_lds,
        16, 0, 0);
}

// ---------------- transpose + fp32->bf16 convert: out[c][r] = in[r][c] ----------------
__global__ __launch_bounds__(256) void transpose_cvt(
    const float* __restrict__ in, bf16* __restrict__ out,
    int R, int Ccols, size_t ibs, size_t obs)
{
    __shared__ float tile[32][33];
    const float* ib = in + (size_t)blockIdx.z * ibs;
    bf16* ob = out + (size_t)blockIdx.z * obs;
    int c0 = blockIdx.x * 32, r0 = blockIdx.y * 32;
    int tx = threadIdx.x & 31, ty = threadIdx.x >> 5;
    #pragma unroll
    for (int i = 0; i < 32; i += 8)
        tile[ty + i][tx] = ib[(size_t)(r0 + ty + i) * Ccols + c0 + tx];
    __syncthreads();
    #pragma unroll
    for (int i = 0; i < 32; i += 8)
        ob[(size_t)(c0 + ty + i) * R + r0 + tx] = f2bf(tile[tx][ty + i]);
}

// ---------------- 4 weight transposes in one launch (z selects weight) ----------------
__global__ __launch_bounds__(256) void transpose_w4(
    const float* __restrict__ p0, const float* __restrict__ p1,
    const float* __restrict__ p2, const float* __restrict__ p3,
    bf16* __restrict__ out)
{
    __shared__ float tile[32][33];
    int z = blockIdx.z;
    const float* ib = (z == 0) ? p0 : (z == 1) ? p1 : (z == 2) ? p2 : p3;
    bf16* ob = out + (size_t)z * 1048576;
    int c0 = blockIdx.x * 32, r0 = blockIdx.y * 32;
    int tx = threadIdx.x & 31, ty = threadIdx.x >> 5;
    #pragma unroll
    for (int i = 0; i < 32; i += 8)
        tile[ty + i][tx] = ib[(size_t)(r0 + ty + i) * 1024 + c0 + tx];
    __syncthreads();
    #pragma unroll
    for (int i = 0; i < 32; i += 8)
        ob[(size_t)(c0 + ty + i) * 1024 + r0 + tx] = f2bf(tile[tx][ty + i]);
}

// ---------------- 3x3 s2 avg pool (count_include_pad), xt[B*N][C] -> xp[B*qN][C] ------
__global__ __launch_bounds__(256) void pool_kernel(const bf16* __restrict__ xt,
                                                   bf16* __restrict__ xp)
{
    int bqn = blockIdx.x;
    int b = bqn / QN, qn = bqn % QN;
    int y = qn / QH, x = qn % QH;
    int t = threadIdx.x;
    float s0 = 0, s1 = 0, s2 = 0, s3 = 0;
    for (int dy = 0; dy < 3; dy++) {
        int hy = 2 * y - 1 + dy;
        if (hy < 0 || hy >= HW) continue;
        for (int dx = 0; dx < 3; dx++) {
            int hx = 2 * x - 1 + dx;
            if (hx < 0 || hx >= HW) continue;
            const bf16* row = xt + (size_t)(b * NTOK + hy * HW + hx) * C_;
            s0 += bf2f(row[t]);
            s1 += bf2f(row[t + 256]);
            s2 += bf2f(row[t + 512]);
            s3 += bf2f(row[t + 768]);
        }
    }
    bf16* o = xp + (size_t)bqn * C_;
    const float n = 1.f / 9.f;
    o[t] = f2bf(s0 * n); o[t + 256] = f2bf(s1 * n);
    o[t + 512] = f2bf(s2 * n); o[t + 768] = f2bf(s3 * n);
}

// ---------------- NT GEMM: C[m][n] = sum_k A[m][k]*Bt[n][k], K=1024 -------------------
// EPI 0: bf16 row-major [M][1024]
// EPI 2: fp32 out + bias: row=channel, col=token -> out[b*147456 + ch*144 + qn]
// EPI 3: K frag-ready (32-key tiles): row=token(b*576+n), col=channel
// EPI 4: V frag-ready (32-key tiles): row=channel, col=token(b*576+n)
template<int EPI>
__global__ __launch_bounds__(256, 2) void gemm_nt(
    const bf16* __restrict__ A, const bf16* __restrict__ Bt,
    void* __restrict__ Cout, const float* __restrict__ bias)
{
    __shared__ bf16 lds[2][2][128 * 64];
    const int tid = threadIdx.x;
    const int wv = tid >> 6, ln = tid & 63;
    const int m0 = blockIdx.x * 128, n0 = blockIdx.y * 128;
    const int wr = wv >> 1, wc = wv & 1;
    const int l15 = ln & 15, l4 = ln >> 4;
    const int r8 = ln >> 3, sl = ln & 7;
    const int sg = sl ^ r8;

    const bf16* gA = A + (size_t)m0 * C_;
    const bf16* gB = Bt + (size_t)n0 * C_;

    f32x4 zero = {0.f, 0.f, 0.f, 0.f};
    f32x4 acc[4][4];
    #pragma unroll
    for (int i = 0; i < 4; i++)
        #pragma unroll
        for (int j = 0; j < 4; j++) acc[i][j] = zero;

    auto stage = [&](int kt, int d) {
        const bf16* sa = gA + kt * 64;
        const bf16* sb = gB + kt * 64;
        bf16* la = lds[d][0];
        bf16* lb = lds[d][1];
        #pragma unroll
        for (int i = 0; i < 4; i++) {
            int chunk = wv * 4 + i;
            gll16(sa + (size_t)(chunk * 8 + r8) * C_ + sg * 8, la + chunk * 512);
            gll16(sb + (size_t)(chunk * 8 + r8) * C_ + sg * 8, lb + chunk * 512);
        }
    };

    stage(0, 0);
    asm volatile("s_waitcnt vmcnt(0)");
    __syncthreads();

    int cur = 0;
    for (int kt = 0; kt < 16; kt++) {
        if (kt < 15) stage(kt + 1, cur ^ 1);
        const bf16* la = lds[cur][0];
        const bf16* lb = lds[cur][1];
        #pragma unroll
        for (int ks = 0; ks < 2; ks++) {
            short8 af[4], bfr[4];
            #pragma unroll
            for (int fm = 0; fm < 4; fm++) {
                int row = wr * 64 + fm * 16 + l15;
                int slot = (ks * 4 + l4) ^ (row & 7);
                af[fm] = *(const short8*)((const char*)la + row * 128 + slot * 16);
            }
            #pragma unroll
            for (int fn = 0; fn < 4; fn++) {
                int row = wc * 64 + fn * 16 + l15;
                int slot = (ks * 4 + l4) ^ (row & 7);
                bfr[fn] = *(const short8*)((const char*)lb + row * 128 + slot * 16);
            }
            #pragma unroll
            for (int fm = 0; fm < 4; fm++)
                #pragma unroll
                for (int fn = 0; fn < 4; fn++)
                    acc[fm][fn] = MFMA(af[fm], bfr[fn], acc[fm][fn]);
        }
        asm volatile("s_waitcnt vmcnt(0)");
        __syncthreads();
        cur ^= 1;
    }

    #pragma unroll
    for (int fm = 0; fm < 4; fm++) {
        #pragma unroll
        for (int fn = 0; fn < 4; fn++) {
            #pragma unroll
            for (int r = 0; r < 4; r++) {
                int row = m0 + wr * 64 + fm * 16 + l4 * 4 + r;
                int col = n0 + wc * 64 + fn * 16 + l15;
                float v = acc[fm][fn][r];
                if constexpr (EPI == 0) {
                    ((bf16*)Cout)[(size_t)row * C_ + col] = f2bf(v);
                } else if constexpr (EPI == 2) {
                    int bb = col / QN, qn = col % QN;
                    ((float*)Cout)[(size_t)bb * (C_ * QN) + (size_t)row * QN + qn] =
                        v + bias[row];
                } else if constexpr (EPI == 3) {
                    // K frag-ready: row = global token, col = channel
                    int b = row / NTOK, n = row % NTOK;
                    int h = col >> 7, ci = col & 127;
                    int kt2 = n >> 5, kf = (n >> 4) & 1, klane = n & 15;
                    int ks2 = ci >> 5, chunk = (ci >> 3) & 3, e = ci & 7;
                    int lane = chunk * 16 + klane;
                    size_t addr = ((((size_t)(b * NH + h) * 18 + kt2) * 2 + kf) * 4 + ks2) * 512
                                  + lane * 8 + e;
                    ((bf16*)Cout)[addr] = f2bf(v);
                } else {
                    // V frag-ready: row = channel, col = global token
                    int b = col / NTOK, n = col % NTOK;
                    int h = row >> 7, ci = row & 127;
                    int hf = (ci >> 4) & 7, lanelo = ci & 15;
                    int kt2 = n >> 5, chunk = (n >> 3) & 3, e = n & 7;
                    int lane = chunk * 16 + lanelo;
                    size_t addr = (((size_t)(b * NH + h) * 18 + kt2) * 8 + hf) * 512
                                  + lane * 8 + e;
                    ((bf16*)Cout)[addr] = f2bf(v);
                }
            }
        }
    }
}

// ---------------- rel-pos bias tables -> global bf16 [head][144][24] x2 --------------
__global__ __launch_bounds__(192) void relgen_kernel(
    const bf16* __restrict__ qbuf, const float* __restrict__ rph,
    const float* __restrict__ rpw, bf16* __restrict__ rgh, bf16* __restrict__ rgw)
{
    const int bh = blockIdx.x;
    const int b = bh >> 3, h = bh & 7;
    const bf16* qhb = qbuf + ((size_t)(b * QN) * C_ + h * HD);
    bf16* oh = rgh + (size_t)bh * (QN * 24);
    bf16* ow = rgw + (size_t)bh * (QN * 24);

    #pragma unroll
    for (int rep = 0; rep < 3; rep++) {
        int t = threadIdx.x;
        int qr = (t >> 2) + rep * 48;
        int kkg = t & 3;
        int y = qr / 12, x = qr - (qr / 12) * 12;
        const short8* qrow = (const short8*)(qhb + (size_t)qr * C_);
        float sh[6] = {0, 0, 0, 0, 0, 0}, sw[6] = {0, 0, 0, 0, 0, 0};
        for (int c0 = 0; c0 < 16; c0++) {
            short8 qv = qrow[c0];
            float qf[8];
            #pragma unroll
            for (int j = 0; j < 8; j++) qf[j] = s2f(qv[j]);
            #pragma unroll
            for (int j = 0; j < 6; j++) {
                int kk = j * 4 + kkg;
                const f32x4* rh = (const f32x4*)(rph + (size_t)(2 * y - kk + 23) * HD + c0 * 8);
                const f32x4* rw = (const f32x4*)(rpw + (size_t)(2 * x - kk + 23) * HD + c0 * 8);
                f32x4 h0 = rh[0], h1 = rh[1], w0 = rw[0], w1 = rw[1];
                #pragma unroll
                for (int u = 0; u < 4; u++) {
                    sh[j] = fmaf(qf[u], h0[u], sh[j]);
                    sw[j] = fmaf(qf[u], w0[u], sw[j]);
                    sh[j] = fmaf(qf[u + 4], h1[u], sh[j]);
                    sw[j] = fmaf(qf[u + 4], w1[u], sw[j]);
                }
            }
        }
        #pragma unroll
        for (int j = 0; j < 6; j++) {
            oh[qr * 24 + j * 4 + kkg] = f2bf(sh[j]);
            ow[qr * 24 + j * 4 + kkg] = f2bf(sw[j]);
        }
    }
}

// ---------------- QK^T + scale + bias -> S bf16 [lbh][144][576] ------------------------
// grid: (4 f-chunks, 512 heads) x 192 thr; wave owns 48 q-rows (3 slabs), 9 f-iters.
__global__ __launch_bounds__(192) void qk_kernel(
    const bf16* __restrict__ qbuf, const bf16* __restrict__ kfr,
    const bf16* __restrict__ rgh, const bf16* __restrict__ rgw,
    bf16* __restrict__ S, int bh0)
{
    __shared__ bf16 relhL[QN * 24];   // 6.75 KB
    __shared__ bf16 relwL[QN * 24];   // 6.75 KB

    const int fc = blockIdx.x;
    const int lbh = blockIdx.y;
    const int bh = bh0 + lbh;
    const int b = bh >> 3, h = bh & 7;
    const int w = threadIdx.x >> 6, ln = threadIdx.x & 63;
    const int l15 = ln & 15, l4 = ln >> 4;

    const bf16* qhb = qbuf + ((size_t)(b * QN) * C_ + h * HD);
    const bf16* kh = kfr + (size_t)bh * 18 * 4096;
    bf16* Sh = S + (size_t)lbh * QN * NTOK;

    // copy this head's bias tables to LDS (432 short8 each)
    {
        const short8* gh = (const short8*)(rgh + (size_t)bh * (QN * 24));
        const short8* gw = (const short8*)(rgw + (size_t)bh * (QN * 24));
        for (int i = threadIdx.x; i < 432; i += 192) {
            ((short8*)relhL)[i] = gh[i];
            ((short8*)relwL)[i] = gw[i];
        }
    }
    __syncthreads();

    // persistent q fragments: 3 slabs (B-operand: col=q=l15, k=ks*32+l4*8+e)
    short8 qfr[3][4];
    #pragma unroll
    for (int s = 0; s < 3; s++)
        #pragma unroll
        for (int ks = 0; ks < 4; ks++)
            qfr[s][ks] = *(const short8*)(qhb + (size_t)(w * 48 + s * 16 + l15) * C_ +
                                          ks * 32 + l4 * 8);

    f32x4 zero = {0.f, 0.f, 0.f, 0.f};
    const float scale = 0.08838834764831845f;  // 1/sqrt(128)

    for (int f = fc * 9; f < fc * 9 + 9; f++) {
        short8 kb[4];
        #pragma unroll
        for (int ks = 0; ks < 4; ks++)
            kb[ks] = *(const short8*)(kh + (size_t)f * 2048 + ks * 512 + ln * 8);
        #pragma unroll
        for (int s = 0; s < 3; s++) {
            f32x4 acc = zero;
            #pragma unroll
            for (int ks = 0; ks < 4; ks++) acc = MFMA(kb[ks], qfr[s][ks], acc);
            int qrow = w * 48 + s * 16 + l15;
            s16x4 o;
            #pragma unroll
            for (int r = 0; r < 4; r++) {
                int key = f * 16 + l4 * 4 + r;
                int kr = key / 24, kc = key - kr * 24;
                o[r] = (short)bfbits(acc[r] * scale + bf2f(relhL[qrow * 24 + kr]) +
                                     bf2f(relwL[qrow * 24 + kc]));
            }
            *(s16x4*)(Sh + (size_t)qrow * NTOK + f * 16 + l4 * 4) = o;
        }
    }
}

// ---------------- softmax (no-max, |S| bounded) + PV + residual ------------------------
// grid: 1536 blocks x 256 thr (4 waves); wave w owns hd fragments {2w, 2w+1}.
// P = exp(S) raw; redundant exp across waves is cheap VALU; zero LDS/barriers.
__global__ __launch_bounds__(256) void sv_kernel(
    const bf16* __restrict__ S, const bf16* __restrict__ vfr,
    const bf16* __restrict__ qbuf, bf16* __restrict__ attno, int bh0)
{
    const int lbh = blockIdx.x / 3, qb = blockIdx.x - lbh * 3;
    const int bh = bh0 + lbh;
    const int b = bh >> 3, h = bh & 7;
    const int w = threadIdx.x >> 6, ln = threadIdx.x & 63;
    const int l15 = ln & 15, l4 = ln >> 4;
    const int hf0 = w * 2;

    const bf16* Sh = S + (size_t)lbh * QN * NTOK;
    const bf16* vh = vfr + (size_t)bh * 18 * 4096;

    f32x4 zero = {0.f, 0.f, 0.f, 0.f};
    f32x4 Of[3][2];
    float ls[3] = {0.f, 0.f, 0.f};
    #pragma unroll
    for (int s = 0; s < 3; s++) { Of[s][0] = zero; Of[s][1] = zero; }

    for (int kt = 0; kt < 18; kt++) {
        short8 vb0 = *(const short8*)(vh + (size_t)kt * 4096 + hf0 * 512 + ln * 8);
        short8 vb1 = *(const short8*)(vh + (size_t)kt * 4096 + (hf0 + 1) * 512 + ln * 8);
        #pragma unroll
        for (int s = 0; s < 3; s++) {
            int qrow = qb * 48 + s * 16 + l15;
            short8 sp = *(const short8*)(Sh + (size_t)qrow * NTOK + kt * 32 + l4 * 8);
            float p[8];
            #pragma unroll
            for (int j = 0; j < 8; j++) p[j] = __expf(s2f(sp[j]));
            ls[s] += ((p[0] + p[1]) + (p[2] + p[3])) + ((p[4] + p[5]) + (p[6] + p[7]));
            short8 pf;
            #pragma unroll
            for (int j = 0; j < 8; j++) pf[j] = (short)bfbits(p[j]);
            Of[s][0] = MFMA(vb0, pf, Of[s][0]);
            Of[s][1] = MFMA(vb1, pf, Of[s][1]);
        }
    }

    // epilogue: row-sum across the 4 lane-groups, O/l + q residual (this wave's 2 hf)
    #pragma unroll
    for (int s = 0; s < 3; s++) {
        float t = ls[s];
        t += __shfl_xor(t, 16, 64);
        t += __shfl_xor(t, 32, 64);
        float inv = 1.f / t;
        int qrow = qb * 48 + s * 16 + l15;
        const bf16* qrb = qbuf + ((size_t)(b * QN + qrow) * C_ + h * HD);
        bf16* orb = attno + ((size_t)(b * QN + qrow) * C_ + h * HD);
        #pragma unroll
        for (int u = 0; u < 2; u++) {
            int hf = hf0 + u;
            s16x4 qres = *(const s16x4*)(qrb + hf * 16 + l4 * 4);
            s16x4 o;
            #pragma unroll
            for (int r = 0; r < 4; r++) {
                float v = Of[s][u][r] * inv + s2f(qres[r]);
                o[r] = (short)bfbits(v);
            }
            *(s16x4*)(orb + hf * 16 + l4 * 4) = o;
        }
    }
}

extern "C" void kernel_launch(void* const* d_in, const int* in_sizes, int n_in,
                              void* d_out, int out_size, void* d_ws, size_t ws_size,
                              hipStream_t stream)
{
    const float* x   = (const float*)d_in[0];
    const float* Wq  = (const float*)d_in[1];
    const float* Wk  = (const float*)d_in[2];
    const float* Wv  = (const float*)d_in[3];
    const float* Wp  = (const float*)d_in[4];
    const float* bp  = (const float*)d_in[5];
    const float* rph = (const float*)d_in[6];
    const float* rpw = (const float*)d_in[7];

    char* ws = (char*)d_ws;
    const size_t MB = 1024 * 1024;
    bf16* Wqt  = (bf16*)(ws + 0 * MB);
    bf16* Wkt  = (bf16*)(ws + 2 * MB);
    bf16* Wvt  = (bf16*)(ws + 4 * MB);
    bf16* Wpt  = (bf16*)(ws + 6 * MB);
    bf16* xt   = (bf16*)(ws + 8 * MB);          // 144 MB (dead after K/V gemms)
    bf16* Sbuf = (bf16*)(ws + 8 * MB);          // 85 MB per pass, overlays dead xt
    bf16* rgh  = (bf16*)(ws + 100 * MB);        // 6.75 MB rel-h tables (overlays xt)
    bf16* rgw  = (bf16*)(ws + 108 * MB);        // 6.75 MB rel-w tables
    bf16* kfrb = (bf16*)(ws + 152 * MB);        // 144 MB (frag-ready K)
    bf16* vfrb = (bf16*)(ws + 296 * MB);        // 144 MB (frag-ready V)
    bf16* xp   = (bf16*)(ws + 440 * MB);        // 36 MB (pool out; reused as attno)
    bf16* qbuf = (bf16*)(ws + 476 * MB);        // 36 MB -> end 512 MB
    bf16* attno = xp;                           // xp dead after q-projection

    transpose_w4<<<dim3(32, 32, 4), 256, 0, stream>>>(Wq, Wk, Wv, Wp, (bf16*)ws);
    transpose_cvt<<<dim3(18, 32, 128), 256, 0, stream>>>(
        x, xt, 1024, 576, (size_t)1024 * 576, (size_t)576 * 1024);
    pool_kernel<<<dim3(B_ * QN), 256, 0, stream>>>(xt, xp);
    gemm_nt<3><<<dim3(576, 8), 256, 0, stream>>>(xt, Wkt, kfrb, nullptr);
    gemm_nt<4><<<dim3(8, 576), 256, 0, stream>>>(Wvt, xt, vfrb, nullptr);
    gemm_nt<0><<<dim3(144, 8), 256, 0, stream>>>(xp, Wqt, qbuf, nullptr);
    relgen_kernel<<<dim3(B_ * NH), 192, 0, stream>>>(qbuf, rph, rpw, rgh, rgw);
    // attention in 2 passes of 512 heads (S buffer 85 MB, L3-resident)
    for (int pass = 0; pass < 2; pass++) {
        qk_kernel<<<dim3(4, 512), 192, 0, stream>>>(qbuf, kfrb, rgh, rgw, Sbuf, pass * 512);
        sv_kernel<<<dim3(1536), 256, 0, stream>>>(Sbuf, vfrb, qbuf, attno, pass * 512);
    }
    gemm_nt<2><<<dim3(8, 144), 256, 0, stream>>>(Wpt, attno, d_out, bp);
}

// Round 12
// 1044.447 us; speedup vs baseline: 1.3259x; 1.3259x over previous
//
#include <hip/hip_runtime.h>
#include <hip/hip_bf16.h>

using bf16 = __hip_bfloat16;
typedef __attribute__((ext_vector_type(8))) short short8;
typedef __attribute__((ext_vector_type(4))) short s16x4;
typedef __attribute__((ext_vector_type(4))) float f32x4;

#define MFMA(a,b,c) __builtin_amdgcn_mfma_f32_16x16x32_bf16(a, b, c, 0, 0, 0)

#define B_      128
#define C_      1024
#define NH      8
#define HD      128
#define HW      24
#define NTOK    576
#define QH      12
#define QN      144

static __device__ __forceinline__ float bf2f(bf16 v) { return __bfloat162float(v); }
static __device__ __forceinline__ bf16  f2bf(float v) { return __float2bfloat16(v); }
static __device__ __forceinline__ float s2f(short s) {
    return __uint_as_float(((unsigned)(unsigned short)s) << 16);
}
static __device__ __forceinline__ unsigned bfbits(float v) {
    bf16 t = f2bf(v);
    return (unsigned)*(unsigned short*)&t;
}

__device__ __forceinline__ void gll16(const bf16* src, bf16* dst_lds) {
    __builtin_amdgcn_global_load_lds(
        (__attribute__((address_space(1))) const unsigned int*)src,
        (__attribute__((address_space(3))) unsigned int*)dst_lds,
        16, 0, 0);
}

// ---------------- transpose + fp32->bf16 convert: out[c][r] = in[r][c] ----------------
__global__ __launch_bounds__(256) void transpose_cvt(
    const float* __restrict__ in, bf16* __restrict__ out,
    int R, int Ccols, size_t ibs, size_t obs)
{
    __shared__ float tile[32][33];
    const float* ib = in + (size_t)blockIdx.z * ibs;
    bf16* ob = out + (size_t)blockIdx.z * obs;
    int c0 = blockIdx.x * 32, r0 = blockIdx.y * 32;
    int tx = threadIdx.x & 31, ty = threadIdx.x >> 5;
    #pragma unroll
    for (int i = 0; i < 32; i += 8)
        tile[ty + i][tx] = ib[(size_t)(r0 + ty + i) * Ccols + c0 + tx];
    __syncthreads();
    #pragma unroll
    for (int i = 0; i < 32; i += 8)
        ob[(size_t)(c0 + ty + i) * R + r0 + tx] = f2bf(tile[tx][ty + i]);
}

// ---------------- 4 weight transposes in one launch (z selects weight) ----------------
__global__ __launch_bounds__(256) void transpose_w4(
    const float* __restrict__ p0, const float* __restrict__ p1,
    const float* __restrict__ p2, const float* __restrict__ p3,
    bf16* __restrict__ out)
{
    __shared__ float tile[32][33];
    int z = blockIdx.z;
    const float* ib = (z == 0) ? p0 : (z == 1) ? p1 : (z == 2) ? p2 : p3;
    bf16* ob = out + (size_t)z * 1048576;
    int c0 = blockIdx.x * 32, r0 = blockIdx.y * 32;
    int tx = threadIdx.x & 31, ty = threadIdx.x >> 5;
    #pragma unroll
    for (int i = 0; i < 32; i += 8)
        tile[ty + i][tx] = ib[(size_t)(r0 + ty + i) * 1024 + c0 + tx];
    __syncthreads();
    #pragma unroll
    for (int i = 0; i < 32; i += 8)
        ob[(size_t)(c0 + ty + i) * 1024 + r0 + tx] = f2bf(tile[tx][ty + i]);
}

// ---------------- 3x3 s2 avg pool (count_include_pad), xt[B*N][C] -> xp[B*qN][C] ------
__global__ __launch_bounds__(256) void pool_kernel(const bf16* __restrict__ xt,
                                                   bf16* __restrict__ xp)
{
    int bqn = blockIdx.x;
    int b = bqn / QN, qn = bqn % QN;
    int y = qn / QH, x = qn % QH;
    int t = threadIdx.x;
    float s0 = 0, s1 = 0, s2 = 0, s3 = 0;
    for (int dy = 0; dy < 3; dy++) {
        int hy = 2 * y - 1 + dy;
        if (hy < 0 || hy >= HW) continue;
        for (int dx = 0; dx < 3; dx++) {
            int hx = 2 * x - 1 + dx;
            if (hx < 0 || hx >= HW) continue;
            const bf16* row = xt + (size_t)(b * NTOK + hy * HW + hx) * C_;
            s0 += bf2f(row[t]);
            s1 += bf2f(row[t + 256]);
            s2 += bf2f(row[t + 512]);
            s3 += bf2f(row[t + 768]);
        }
    }
    bf16* o = xp + (size_t)bqn * C_;
    const float n = 1.f / 9.f;
    o[t] = f2bf(s0 * n); o[t + 256] = f2bf(s1 * n);
    o[t + 512] = f2bf(s2 * n); o[t + 768] = f2bf(s3 * n);
}

// ---------------- NT GEMM: C[m][n] = sum_k A[m][k]*Bt[n][k], K=1024 -------------------
template<int EPI>
__global__ __launch_bounds__(256, 2) void gemm_nt(
    const bf16* __restrict__ A, const bf16* __restrict__ Bt,
    void* __restrict__ Cout, const float* __restrict__ bias)
{
    __shared__ bf16 lds[2][2][128 * 64];
    const int tid = threadIdx.x;
    const int wv = tid >> 6, ln = tid & 63;
    const int m0 = blockIdx.x * 128, n0 = blockIdx.y * 128;
    const int wr = wv >> 1, wc = wv & 1;
    const int l15 = ln & 15, l4 = ln >> 4;
    const int r8 = ln >> 3, sl = ln & 7;
    const int sg = sl ^ r8;

    const bf16* gA = A + (size_t)m0 * C_;
    const bf16* gB = Bt + (size_t)n0 * C_;

    f32x4 zero = {0.f, 0.f, 0.f, 0.f};
    f32x4 acc[4][4];
    #pragma unroll
    for (int i = 0; i < 4; i++)
        #pragma unroll
        for (int j = 0; j < 4; j++) acc[i][j] = zero;

    auto stage = [&](int kt, int d) {
        const bf16* sa = gA + kt * 64;
        const bf16* sb = gB + kt * 64;
        bf16* la = lds[d][0];
        bf16* lb = lds[d][1];
        #pragma unroll
        for (int i = 0; i < 4; i++) {
            int chunk = wv * 4 + i;
            gll16(sa + (size_t)(chunk * 8 + r8) * C_ + sg * 8, la + chunk * 512);
            gll16(sb + (size_t)(chunk * 8 + r8) * C_ + sg * 8, lb + chunk * 512);
        }
    };

    stage(0, 0);
    asm volatile("s_waitcnt vmcnt(0)");
    __syncthreads();

    int cur = 0;
    for (int kt = 0; kt < 16; kt++) {
        if (kt < 15) stage(kt + 1, cur ^ 1);
        const bf16* la = lds[cur][0];
        const bf16* lb = lds[cur][1];
        #pragma unroll
        for (int ks = 0; ks < 2; ks++) {
            short8 af[4], bfr[4];
            #pragma unroll
            for (int fm = 0; fm < 4; fm++) {
                int row = wr * 64 + fm * 16 + l15;
                int slot = (ks * 4 + l4) ^ (row & 7);
                af[fm] = *(const short8*)((const char*)la + row * 128 + slot * 16);
            }
            #pragma unroll
            for (int fn = 0; fn < 4; fn++) {
                int row = wc * 64 + fn * 16 + l15;
                int slot = (ks * 4 + l4) ^ (row & 7);
                bfr[fn] = *(const short8*)((const char*)lb + row * 128 + slot * 16);
            }
            #pragma unroll
            for (int fm = 0; fm < 4; fm++)
                #pragma unroll
                for (int fn = 0; fn < 4; fn++)
                    acc[fm][fn] = MFMA(af[fm], bfr[fn], acc[fm][fn]);
        }
        asm volatile("s_waitcnt vmcnt(0)");
        __syncthreads();
        cur ^= 1;
    }

    #pragma unroll
    for (int fm = 0; fm < 4; fm++) {
        #pragma unroll
        for (int fn = 0; fn < 4; fn++) {
            #pragma unroll
            for (int r = 0; r < 4; r++) {
                int row = m0 + wr * 64 + fm * 16 + l4 * 4 + r;
                int col = n0 + wc * 64 + fn * 16 + l15;
                float v = acc[fm][fn][r];
                if constexpr (EPI == 0) {
                    ((bf16*)Cout)[(size_t)row * C_ + col] = f2bf(v);
                } else if constexpr (EPI == 2) {
                    int bb = col / QN, qn = col % QN;
                    ((float*)Cout)[(size_t)bb * (C_ * QN) + (size_t)row * QN + qn] =
                        v + bias[row];
                } else if constexpr (EPI == 3) {
                    // K frag-ready: row = global token, col = channel
                    int b = row / NTOK, n = row % NTOK;
                    int h = col >> 7, ci = col & 127;
                    int kt2 = n >> 5, kf = (n >> 4) & 1, klane = n & 15;
                    int ks2 = ci >> 5, chunk = (ci >> 3) & 3, e = ci & 7;
                    int lane = chunk * 16 + klane;
                    size_t addr = ((((size_t)(b * NH + h) * 18 + kt2) * 2 + kf) * 4 + ks2) * 512
                                  + lane * 8 + e;
                    ((bf16*)Cout)[addr] = f2bf(v);
                } else {
                    // V frag-ready: row = channel, col = global token
                    int b = col / NTOK, n = col % NTOK;
                    int h = row >> 7, ci = row & 127;
                    int hf = (ci >> 4) & 7, lanelo = ci & 15;
                    int kt2 = n >> 5, chunk = (n >> 3) & 3, e = n & 7;
                    int lane = chunk * 16 + lanelo;
                    size_t addr = (((size_t)(b * NH + h) * 18 + kt2) * 8 + hf) * 512
                                  + lane * 8 + e;
                    ((bf16*)Cout)[addr] = f2bf(v);
                }
            }
        }
    }
}

// ---------------- rel_pos fp32 [47][128] -> bf16 padded [48][128] ----------------------
__global__ __launch_bounds__(256) void relcvt_kernel(
    const float* __restrict__ rph, const float* __restrict__ rpw,
    bf16* __restrict__ relph, bf16* __restrict__ relpw)
{
    int i = blockIdx.x * 256 + threadIdx.x;
    if (i < 6144) {
        bool v = i < 6016;   // 47*128
        relph[i] = v ? f2bf(rph[i]) : f2bf(0.f);
        relpw[i] = v ? f2bf(rpw[i]) : f2bf(0.f);
    }
}

// ---------------- rel tables via MFMA + fused gather -----------------------------------
// grid: B*NH*3 blocks x 192 thr; block=(bh,qb); wave owns 16 q-rows.
// Computes RH[d][q] = rel_pos_h[d] . q for d in [0,48) via 16x16x32 MFMA, then
// gather-stores rgh[bh][qrow][kr] = RH[2y+23-kr] (valid kr only). Same for W.
__global__ __launch_bounds__(192) void relgemm_kernel(
    const bf16* __restrict__ qbuf, const bf16* __restrict__ relph,
    const bf16* __restrict__ relpw, bf16* __restrict__ rgh, bf16* __restrict__ rgw)
{
    const int bid = blockIdx.x;
    const int bh = bid / 3, qb = bid - bh * 3;
    const int b = bh >> 3, h = bh & 7;
    const int w = threadIdx.x >> 6, ln = threadIdx.x & 63;
    const int l15 = ln & 15, l4 = ln >> 4;
    const int qrow = qb * 48 + w * 16 + l15;   // this lane's OUTPUT q-row (B-operand col)
    const int y = qrow / 12, x = qrow - y * 12;

    // q fragment (B-operand: row=q selected by l15 at load; same index here)
    short8 qfr[4];
    #pragma unroll
    for (int ks = 0; ks < 4; ks++)
        qfr[ks] = *(const short8*)(qbuf + (size_t)(b * QN + qrow) * C_ + h * HD +
                                   ks * 32 + l4 * 8);

    f32x4 zero = {0.f, 0.f, 0.f, 0.f};
    bf16* oh = rgh + (size_t)bh * (QN * 24);
    bf16* ow = rgw + (size_t)bh * (QN * 24);

    #pragma unroll
    for (int tile = 0; tile < 3; tile++) {
        short8 rfh[4], rfw[4];
        #pragma unroll
        for (int ks = 0; ks < 4; ks++) {
            rfh[ks] = *(const short8*)(relph + (tile * 16 + l15) * 128 + ks * 32 + l4 * 8);
            rfw[ks] = *(const short8*)(relpw + (tile * 16 + l15) * 128 + ks * 32 + l4 * 8);
        }
        f32x4 ah = zero, aw = zero;
        #pragma unroll
        for (int ks = 0; ks < 4; ks++) ah = MFMA(rfh[ks], qfr[ks], ah);
        #pragma unroll
        for (int ks = 0; ks < 4; ks++) aw = MFMA(rfw[ks], qfr[ks], aw);
        // lane holds RH[d = tile*16 + l4*4 + r][q = qrow]
        #pragma unroll
        for (int r = 0; r < 4; r++) {
            int d = tile * 16 + l4 * 4 + r;
            int kr = 2 * y + 23 - d;
            if (kr >= 0 && kr < 24) oh[qrow * 24 + kr] = f2bf(ah[r]);
            int kc = 2 * x + 23 - d;
            if (kc >= 0 && kc < 24) ow[qrow * 24 + kc] = f2bf(aw[r]);
        }
    }
}

// ---------------- QK^T + scale + bias -> S bf16 [lbh][144][576] ------------------------
// grid: (4 f-chunks, 512 heads) x 192 thr; wave owns 48 q-rows (3 slabs), 9 f-iters.
__global__ __launch_bounds__(192) void qk_kernel(
    const bf16* __restrict__ qbuf, const bf16* __restrict__ kfr,
    const bf16* __restrict__ rgh, const bf16* __restrict__ rgw,
    bf16* __restrict__ S, int bh0)
{
    __shared__ bf16 relhL[QN * 24];   // 6.75 KB
    __shared__ bf16 relwL[QN * 24];   // 6.75 KB

    const int fc = blockIdx.x;
    const int lbh = blockIdx.y;
    const int bh = bh0 + lbh;
    const int b = bh >> 3, h = bh & 7;
    const int w = threadIdx.x >> 6, ln = threadIdx.x & 63;
    const int l15 = ln & 15, l4 = ln >> 4;

    const bf16* qhb = qbuf + ((size_t)(b * QN) * C_ + h * HD);
    const bf16* kh = kfr + (size_t)bh * 18 * 4096;
    bf16* Sh = S + (size_t)lbh * QN * NTOK;

    // copy this head's bias tables to LDS (432 short8 each)
    {
        const short8* gh = (const short8*)(rgh + (size_t)bh * (QN * 24));
        const short8* gw = (const short8*)(rgw + (size_t)bh * (QN * 24));
        for (int i = threadIdx.x; i < 432; i += 192) {
            ((short8*)relhL)[i] = gh[i];
            ((short8*)relwL)[i] = gw[i];
        }
    }
    __syncthreads();

    // persistent q fragments: 3 slabs (B-operand: col=q=l15, k=ks*32+l4*8+e)
    short8 qfr[3][4];
    #pragma unroll
    for (int s = 0; s < 3; s++)
        #pragma unroll
        for (int ks = 0; ks < 4; ks++)
            qfr[s][ks] = *(const short8*)(qhb + (size_t)(w * 48 + s * 16 + l15) * C_ +
                                          ks * 32 + l4 * 8);

    f32x4 zero = {0.f, 0.f, 0.f, 0.f};
    const float scale = 0.08838834764831845f;  // 1/sqrt(128)

    for (int f = fc * 9; f < fc * 9 + 9; f++) {
        short8 kb[4];
        #pragma unroll
        for (int ks = 0; ks < 4; ks++)
            kb[ks] = *(const short8*)(kh + (size_t)f * 2048 + ks * 512 + ln * 8);
        #pragma unroll
        for (int s = 0; s < 3; s++) {
            f32x4 acc = zero;
            #pragma unroll
            for (int ks = 0; ks < 4; ks++) acc = MFMA(kb[ks], qfr[s][ks], acc);
            int qrow = w * 48 + s * 16 + l15;
            s16x4 o;
            #pragma unroll
            for (int r = 0; r < 4; r++) {
                int key = f * 16 + l4 * 4 + r;
                int kr = key / 24, kc = key - kr * 24;
                o[r] = (short)bfbits(acc[r] * scale + bf2f(relhL[qrow * 24 + kr]) +
                                     bf2f(relwL[qrow * 24 + kc]));
            }
            *(s16x4*)(Sh + (size_t)qrow * NTOK + f * 16 + l4 * 4) = o;
        }
    }
}

// ---------------- softmax (no-max, |S| bounded) + PV + residual ------------------------
// grid: 1536 blocks x 256 thr (4 waves); wave w owns hd fragments {2w, 2w+1}.
__global__ __launch_bounds__(256) void sv_kernel(
    const bf16* __restrict__ S, const bf16* __restrict__ vfr,
    const bf16* __restrict__ qbuf, bf16* __restrict__ attno, int bh0)
{
    const int lbh = blockIdx.x / 3, qb = blockIdx.x - lbh * 3;
    const int bh = bh0 + lbh;
    const int b = bh >> 3, h = bh & 7;
    const int w = threadIdx.x >> 6, ln = threadIdx.x & 63;
    const int l15 = ln & 15, l4 = ln >> 4;
    const int hf0 = w * 2;

    const bf16* Sh = S + (size_t)lbh * QN * NTOK;
    const bf16* vh = vfr + (size_t)bh * 18 * 4096;

    f32x4 zero = {0.f, 0.f, 0.f, 0.f};
    f32x4 Of[3][2];
    float ls[3] = {0.f, 0.f, 0.f};
    #pragma unroll
    for (int s = 0; s < 3; s++) { Of[s][0] = zero; Of[s][1] = zero; }

    for (int kt = 0; kt < 18; kt++) {
        short8 vb0 = *(const short8*)(vh + (size_t)kt * 4096 + hf0 * 512 + ln * 8);
        short8 vb1 = *(const short8*)(vh + (size_t)kt * 4096 + (hf0 + 1) * 512 + ln * 8);
        #pragma unroll
        for (int s = 0; s < 3; s++) {
            int qrow = qb * 48 + s * 16 + l15;
            short8 sp = *(const short8*)(Sh + (size_t)qrow * NTOK + kt * 32 + l4 * 8);
            float p[8];
            #pragma unroll
            for (int j = 0; j < 8; j++) p[j] = __expf(s2f(sp[j]));
            ls[s] += ((p[0] + p[1]) + (p[2] + p[3])) + ((p[4] + p[5]) + (p[6] + p[7]));
            short8 pf;
            #pragma unroll
            for (int j = 0; j < 8; j++) pf[j] = (short)bfbits(p[j]);
            Of[s][0] = MFMA(vb0, pf, Of[s][0]);
            Of[s][1] = MFMA(vb1, pf, Of[s][1]);
        }
    }

    // epilogue: row-sum across the 4 lane-groups, O/l + q residual (this wave's 2 hf)
    #pragma unroll
    for (int s = 0; s < 3; s++) {
        float t = ls[s];
        t += __shfl_xor(t, 16, 64);
        t += __shfl_xor(t, 32, 64);
        float inv = 1.f / t;
        int qrow = qb * 48 + s * 16 + l15;
        const bf16* qrb = qbuf + ((size_t)(b * QN + qrow) * C_ + h * HD);
        bf16* orb = attno + ((size_t)(b * QN + qrow) * C_ + h * HD);
        #pragma unroll
        for (int u = 0; u < 2; u++) {
            int hf = hf0 + u;
            s16x4 qres = *(const s16x4*)(qrb + hf * 16 + l4 * 4);
            s16x4 o;
            #pragma unroll
            for (int r = 0; r < 4; r++) {
                float v = Of[s][u][r] * inv + s2f(qres[r]);
                o[r] = (short)bfbits(v);
            }
            *(s16x4*)(orb + hf * 16 + l4 * 4) = o;
        }
    }
}

extern "C" void kernel_launch(void* const* d_in, const int* in_sizes, int n_in,
                              void* d_out, int out_size, void* d_ws, size_t ws_size,
                              hipStream_t stream)
{
    const float* x   = (const float*)d_in[0];
    const float* Wq  = (const float*)d_in[1];
    const float* Wk  = (const float*)d_in[2];
    const float* Wv  = (const float*)d_in[3];
    const float* Wp  = (const float*)d_in[4];
    const float* bp  = (const float*)d_in[5];
    const float* rph = (const float*)d_in[6];
    const float* rpw = (const float*)d_in[7];

    char* ws = (char*)d_ws;
    const size_t MB = 1024 * 1024;
    bf16* Wqt  = (bf16*)(ws + 0 * MB);
    bf16* Wkt  = (bf16*)(ws + 2 * MB);
    bf16* Wvt  = (bf16*)(ws + 4 * MB);
    bf16* Wpt  = (bf16*)(ws + 6 * MB);
    bf16* xt   = (bf16*)(ws + 8 * MB);          // 144 MB (dead after K/V gemms)
    bf16* Sbuf = (bf16*)(ws + 8 * MB);          // 85 MB per pass, overlays dead xt
    bf16* rgh  = (bf16*)(ws + 100 * MB);        // 6.75 MB rel-h tables (overlays xt)
    bf16* rgw  = (bf16*)(ws + 108 * MB);        // 6.75 MB rel-w tables
    bf16* relph = (bf16*)(ws + 116 * MB);       // 12 KB padded rel_pos_h bf16
    bf16* relpw = (bf16*)(ws + 117 * MB);       // 12 KB padded rel_pos_w bf16
    bf16* kfrb = (bf16*)(ws + 152 * MB);        // 144 MB (frag-ready K)
    bf16* vfrb = (bf16*)(ws + 296 * MB);        // 144 MB (frag-ready V)
    bf16* xp   = (bf16*)(ws + 440 * MB);        // 36 MB (pool out; reused as attno)
    bf16* qbuf = (bf16*)(ws + 476 * MB);        // 36 MB -> end 512 MB
    bf16* attno = xp;                           // xp dead after q-projection

    transpose_w4<<<dim3(32, 32, 4), 256, 0, stream>>>(Wq, Wk, Wv, Wp, (bf16*)ws);
    transpose_cvt<<<dim3(18, 32, 128), 256, 0, stream>>>(
        x, xt, 1024, 576, (size_t)1024 * 576, (size_t)576 * 1024);
    pool_kernel<<<dim3(B_ * QN), 256, 0, stream>>>(xt, xp);
    gemm_nt<3><<<dim3(576, 8), 256, 0, stream>>>(xt, Wkt, kfrb, nullptr);
    gemm_nt<4><<<dim3(8, 576), 256, 0, stream>>>(Wvt, xt, vfrb, nullptr);
    gemm_nt<0><<<dim3(144, 8), 256, 0, stream>>>(xp, Wqt, qbuf, nullptr);
    relcvt_kernel<<<dim3(24), 256, 0, stream>>>(rph, rpw, relph, relpw);
    relgemm_kernel<<<dim3(B_ * NH * 3), 192, 0, stream>>>(qbuf, relph, relpw, rgh, rgw);
    // attention in 2 passes of 512 heads (S buffer 85 MB, L3-resident)
    for (int pass = 0; pass < 2; pass++) {
        qk_kernel<<<dim3(4, 512), 192, 0, stream>>>(qbuf, kfrb, rgh, rgw, Sbuf, pass * 512);
        sv_kernel<<<dim3(1536), 256, 0, stream>>>(Sbuf, vfrb, qbuf, attno, pass * 512);
    }
    gemm_nt<2><<<dim3(8, 144), 256, 0, stream>>>(Wpt, attno, d_out, bp);
}